// Round 9
// baseline (3473.253 us; speedup 1.0000x reference)
//
#include <hip/hip_runtime.h>
#include <hip/hip_bf16.h>

#define IDIM 80
#define HDIM 512
#define ODIM 128
#define G5   5
#define BB   512
#define TT   512
#define PDIM 1285          // G*2*ODIM + G
#define GDIM 1536          // 3*HDIM
#define NB   16            // persistent blocks
#define EPB  32            // h-elements per block
#define PCPB 81            // proj cols per block (16*81 >= 1285)

__device__ __forceinline__ int PHYS(int j) { return (j >> 5) * 36 + (j & 31); }

// Persistent GRU. Block nb owns h-elements [nb*32, nb*32+32).
// Per element e: 3 gate rows computed in PARALLEL by 12 lanes of one wave
// (4 lanes/row, K=128 each), gathered by in-wave shuffles; leader lane
// applies the gates and publishes h_new as ONE tagged 8-byte AGENT word on
// its OWN 64B cacheline. Every thread polls one word (8192 streams over 512
// lines). xp is block-private (phase 0), so no grid barrier anywhere.
// Proj GEMM fused into the poll-idle window with L2-streamed weights.
__global__ void __launch_bounds__(512) gru_kernel(
    const float* __restrict__ ys, const float* __restrict__ W_ih,
    const float* __restrict__ W_hh, const float* __restrict__ b_ih,
    const float* __restrict__ b_hh, const float* __restrict__ W_proj,
    const float* __restrict__ b_proj,
    unsigned long long* __restrict__ hOut, float* __restrict__ xp_loc,
    float* __restrict__ params)
{
  const int tid  = threadIdx.x;
  const int nb   = blockIdx.x;
  const int lane = tid & 63;
  const int wv   = tid >> 6;
  const int grpE = lane / 12;          // 0..5 (valid < 4)
  const int sub  = lane % 12;
  const int g    = sub >> 2;           // gate 0..2
  const int kq   = lane & 3;           // K-quarter
  const int e    = wv * 4 + grpE;      // block-local element (valid < 32)
  const int jglob = nb * EPB + e;
  const bool lead = (sub == 0) && (grpE < 4);

  __shared__ float hs[2][16 * 36];     // h double buffer, padded stride 36
  __shared__ float wih[96 * 82];       // phase-0 W_ih rows
  __shared__ float bihs[96];

  // W_hh slice: row = g*512 + jglob, cols [kq*128, kq*128+128) -> 32 float4
  int row = g * HDIM + nb * EPB + e; if (row > GDIM - 1) row = GDIM - 1;
  float4 wreg[32];
  {
    const float4* wr = (const float4*)(W_hh + (size_t)row * HDIM) + kq * 32;
    #pragma unroll
    for (int i = 0; i < 32; ++i) wreg[i] = wr[i];
  }
  const float bias_r = b_hh[row];

  for (int w = tid; w < 16 * 36; w += 512) { hs[0][w] = 0.f; hs[1][w] = 0.f; }

  // ---- phase 0: block-private xp rows (96) for all 512 batches ----
  for (int idx = tid; idx < 96 * IDIM; idx += 512) {
    int g32 = idx / IDIM, f = idx - g32 * IDIM;
    int rr = (g32 >> 5) * HDIM + nb * EPB + (g32 & 31);
    wih[g32 * 82 + f] = W_ih[(size_t)rr * IDIM + f];
  }
  if (tid < 96) {
    int rr = (tid >> 5) * HDIM + nb * EPB + (tid & 31);
    bihs[tid] = b_ih[rr];
  }
  __syncthreads();
  {
    const int g5 = tid & 31, bs = tid >> 5;
    float* xpl = xp_loc + (size_t)nb * BB * 96;
    for (int gp = 0; gp < 3; ++gp) {
      int g32 = gp * 32 + g5;
      for (int pass = 0; pass < 32; ++pass) {
        int b = pass * 16 + bs;
        const float* yrow = ys + ((size_t)b * TT + TT - 1) * IDIM;
        float acc = bihs[g32];
        #pragma unroll
        for (int f = 0; f < IDIM; f += 2) {
          float2 w2 = *(const float2*)&wih[g32 * 82 + f];
          float2 yv = *(const float2*)&yrow[f];
          acc += w2.x * yv.x + w2.y * yv.y;
        }
        xpl[(size_t)b * 96 + g32] = acc;   // plain: same-CU producer/consumer
      }
    }
  }
  __syncthreads();                         // xp_loc + hs init complete

  const float* xpl = xp_loc + (size_t)nb * BB * 96;
  float xr_c = 0.f, xz_c = 0.f, xn_c = 0.f;
  if (lead) { xr_c = xpl[e]; xz_c = xpl[32 + e]; xn_c = xpl[64 + e]; }

  const int j  = tid;                      // polled h element
  const int jp = PHYS(j);

  for (int b = 0; b < BB; ++b) {
    const int cur = b & 1, nxt = cur ^ 1;

    // prefetch next step's xp (hidden under matvec/poll)
    float xr_n = 0.f, xz_n = 0.f, xn_n = 0.f;
    if (lead && b + 1 < BB) {
      const float* xq = xpl + (size_t)(b + 1) * 96;
      xr_n = xq[e]; xz_n = xq[32 + e]; xn_n = xq[64 + e];
    }

    // matvec partial: this lane's 128 cols of its gate row
    float a0 = 0.f, a1 = 0.f, a2 = 0.f, a3 = 0.f;
    #pragma unroll
    for (int grp = 0; grp < 4; ++grp) {
      const float4* hb = (const float4*)&hs[cur][(kq * 4 + grp) * 36];
      #pragma unroll
      for (int i = 0; i < 8; ++i) {
        float4 h4 = hb[i]; float4 w4 = wreg[grp * 8 + i];
        a0 += w4.x * h4.x; a1 += w4.y * h4.y;
        a2 += w4.z * h4.z; a3 += w4.w * h4.w;
      }
    }
    float dot = (a0 + a1) + (a2 + a3);
    dot += __shfl_xor(dot, 1);
    dot += __shfl_xor(dot, 2);
    dot += bias_r;                          // kq==0 lanes: biased row dot

    // gather the 3 gate dots to the element leader (same wave)
    const int base = (lane / 12) * 12;
    float d1 = __shfl(dot, base + 4);
    float d2 = __shfl(dot, base + 8);

    if (lead) {
      float h_old = hs[cur][PHYS(jglob)];
      float r = 1.f / (1.f + __expf(-(xr_c + dot)));
      float z = 1.f / (1.f + __expf(-(xz_c + d1)));
      float e2 = __expf(2.f * (xn_c + r * d2));
      float n = 1.f - 2.f / (e2 + 1.f);     // tanh, overflow-safe
      float hnew = (1.f - z) * n + z * h_old;
      union { float f; unsigned u; } cv; cv.f = hnew;
      unsigned long long pv = ((unsigned long long)(unsigned)b << 32) | cv.u;
      __hip_atomic_store(&hOut[((size_t)cur * HDIM + jglob) * 8], pv,
                         __ATOMIC_RELAXED, __HIP_MEMORY_SCOPE_AGENT);
    }

    // proj for row b-1 in the poll-idle window (weights streamed from L2)
    if (b >= 1 && tid < 4 * PCPB) {
      int col = tid >> 2, kq2 = tid & 3, gcol = nb * PCPB + col;
      if (gcol < PDIM) {
        const float4* wp = (const float4*)(W_proj + (size_t)gcol * HDIM) + kq2 * 32;
        float p0 = 0.f, p1 = 0.f, p2 = 0.f, p3 = 0.f;
        #pragma unroll
        for (int grp = 0; grp < 4; ++grp) {
          const float4* hb = (const float4*)&hs[cur][(kq2 * 4 + grp) * 36];
          #pragma unroll
          for (int i = 0; i < 8; ++i) {
            float4 h4 = hb[i]; float4 w4 = wp[grp * 8 + i];
            p0 += w4.x * h4.x; p1 += w4.y * h4.y;
            p2 += w4.z * h4.z; p3 += w4.w * h4.w;
          }
        }
        float pr = (p0 + p1) + (p2 + p3);
        pr += __shfl_xor(pr, 1);
        pr += __shfl_xor(pr, 2);
        if (kq2 == 0) params[(size_t)(b - 1) * PDIM + gcol] = pr + b_proj[gcol];
      }
    }

    // poll my h word (own 64B line; AGENT load, proven)
    unsigned long long v; int guard = 0;
    do {
      v = __hip_atomic_load(&hOut[((size_t)cur * HDIM + j) * 8],
                            __ATOMIC_RELAXED, __HIP_MEMORY_SCOPE_AGENT);
    } while ((unsigned)(v >> 32) != (unsigned)b && ++guard < (1 << 20));
    union { unsigned u; float f; } hv; hv.u = (unsigned)v;
    hs[nxt][jp] = hv.f;

    xr_c = xr_n; xz_c = xz_n; xn_c = xn_n;
    __syncthreads();                        // h(b+1) complete
  }

  // epilogue: proj row 511 from hs[0] (= h after step 511)
  if (tid < 4 * PCPB) {
    int col = tid >> 2, kq2 = tid & 3, gcol = nb * PCPB + col;
    if (gcol < PDIM) {
      const float4* wp = (const float4*)(W_proj + (size_t)gcol * HDIM) + kq2 * 32;
      float p0 = 0.f, p1 = 0.f, p2 = 0.f, p3 = 0.f;
      #pragma unroll
      for (int grp = 0; grp < 4; ++grp) {
        const float4* hb = (const float4*)&hs[0][(kq2 * 4 + grp) * 36];
        #pragma unroll
        for (int i = 0; i < 8; ++i) {
          float4 h4 = hb[i]; float4 w4 = wp[grp * 8 + i];
          p0 += w4.x * h4.x; p1 += w4.y * h4.y;
          p2 += w4.z * h4.z; p3 += w4.w * h4.w;
        }
      }
      float pr = (p0 + p1) + (p2 + p3);
      pr += __shfl_xor(pr, 1);
      pr += __shfl_xor(pr, 2);
      if (kq2 == 0) params[(size_t)(BB - 1) * PDIM + gcol] = pr + b_proj[gcol];
    }
  }
}

// samples[b,o] = sum_i w_i * (mu_i + (var_i+1e-6)*eps[i,b,o])
__global__ void mix_kernel(const float* __restrict__ params,
                           const float* __restrict__ eps,
                           float* __restrict__ out)
{
  int b = blockIdx.x, o = threadIdx.x;
  const float* pr = params + (size_t)b * PDIM;
  float s = 0.f;
  #pragma unroll
  for (int i = 0; i < G5; ++i) {
    float mu  = pr[i * ODIM + o];
    float var = pr[2 * i * ODIM + o] + 1e-6f;
    float w   = pr[2 * G5 * ODIM + i];
    float e   = eps[((size_t)i * BB + b) * ODIM + o];
    s += w * (mu + var * e);
  }
  out[(size_t)b * ODIM + o] = s;
}

extern "C" void kernel_launch(void* const* d_in, const int* in_sizes, int n_in,
                              void* d_out, int out_size, void* d_ws, size_t ws_size,
                              hipStream_t stream) {
  const float* ys     = (const float*)d_in[0];
  const float* W_ih   = (const float*)d_in[1];
  const float* W_hh   = (const float*)d_in[2];
  const float* b_ih   = (const float*)d_in[3];
  const float* b_hh   = (const float*)d_in[4];
  const float* W_proj = (const float*)d_in[5];
  const float* b_proj = (const float*)d_in[6];
  const float* eps    = (const float*)d_in[7];
  float* out = (float*)d_out;

  // workspace layout
  char* ws = (char*)d_ws;
  unsigned long long* hOut = (unsigned long long*)ws;   // 2*512 lines * 64B = 64 KB
  float* xp_loc = (float*)(ws + 2 * HDIM * 8 * 8);      // 16*512*96 floats = 3 MB
  float* params = xp_loc + (size_t)NB * BB * 96;        // 512*1285 floats

  hipMemsetAsync(hOut, 0xFF, 2 * HDIM * 8 * 8, stream); // tags invalid

  gru_kernel<<<NB, 512, 0, stream>>>(ys, W_ih, W_hh, b_ih, b_hh,
                                     W_proj, b_proj, hOut, xp_loc, params);

  mix_kernel<<<BB, ODIM, 0, stream>>>(params, eps, out);
}

// Round 10
// 1232.159 us; speedup vs baseline: 2.8188x; 2.8188x over previous
//
#include <hip/hip_runtime.h>
#include <hip/hip_bf16.h>

#define IDIM 80
#define HDIM 512
#define ODIM 128
#define G5   5
#define BB   512
#define TT   512
#define PDIM 1285          // G*2*ODIM + G
#define GDIM 1536          // 3*HDIM
#define NB   48            // persistent blocks
#define RPB  32            // gh rows per block (1536/48)
#define PCPB 27            // proj cols per block (48*27=1296 >= 1285)

typedef unsigned u32x4 __attribute__((ext_vector_type(4)));

__device__ __forceinline__ void ag_storef(float* p, float v) {
  __hip_atomic_store(p, v, __ATOMIC_RELAXED, __HIP_MEMORY_SCOPE_AGENT);
}
__device__ __forceinline__ void ag_storeu(unsigned long long* p, unsigned long long v) {
  __hip_atomic_store(p, v, __ATOMIC_RELAXED, __HIP_MEMORY_SCOPE_AGENT);
}

// heavy barrier — used ONCE after phase 0 (proven r1/r2/r8)
__device__ __forceinline__ void grid_barrier(unsigned* bar, unsigned target) {
  __syncthreads();
  if (threadIdx.x == 0) {
    __hip_atomic_fetch_add(bar, 1u, __ATOMIC_ACQ_REL, __HIP_MEMORY_SCOPE_AGENT);
    while (__hip_atomic_load(bar, __ATOMIC_ACQUIRE, __HIP_MEMORY_SCOPE_AGENT) < target) {
      __builtin_amdgcn_s_sleep(1);
    }
  }
  __syncthreads();
}

// r8 skeleton (48 blocks, tagged AGENT gh exchange, gates-in-consumer, fused
// VGPR proj) with IF-pressure cuts:
//  - 192 designated pollers/block, one 64B line each (4x dwordx4 sc1), with
//    s_sleep backoff -> gh_lds -> sync -> gates. 9216 poll streams vs 73728.
//  - xp staged into a 48KB LDS slab every 8 steps (6x dwordx4 sc1 per thread,
//    one burst) -> zero per-step xp IF loads.
__global__ void __launch_bounds__(512) gru_kernel(
    const float* __restrict__ ys, const float* __restrict__ W_ih,
    const float* __restrict__ W_hh, const float* __restrict__ b_ih,
    const float* __restrict__ b_hh, const float* __restrict__ W_proj,
    const float* __restrict__ b_proj,
    float* __restrict__ xp, unsigned long long* __restrict__ ghT,
    float* __restrict__ params, unsigned* __restrict__ bar)
{
  const int tid  = threadIdx.x;
  const int nb   = blockIdx.x;
  const int lane = tid & 63;
  const int wave = tid >> 6;
  const int r4   = lane >> 4;      // 0..3  row within wave
  const int c    = lane & 15;      // 0..15 column chunk (32 cols each)
  const int row  = nb * RPB + wave * 4 + r4;

  __shared__ float xpl[8 * GDIM];    // 48KB xp slab (8 steps); phase0 wih alias
  __shared__ float gh_lds[GDIM];     // 6KB gh values for current step
  __shared__ float hs[2][16 * 36];   // h double buffer, padded stride 36
  __shared__ float bihs[32];

  // --- W_hh slice -> registers (32 weights/thread, r2/r8 layout) ---
  float4 wreg[8];
  {
    const float4* wrow = (const float4*)(W_hh + (size_t)row * HDIM + c * 32);
    #pragma unroll
    for (int i = 0; i < 8; ++i) wreg[i] = wrow[i];
  }
  const float bhh_r = b_hh[row];

  // --- W_proj slice -> registers: 27 cols/block, 16 threads/col (r8) ---
  const int pcol = nb * PCPB + (tid >> 4);
  const int pcl  = tid & 15;
  const bool pact = (tid < 16 * PCPB) && (pcol < PDIM);
  float4 wp[8] = {};
  float bp = 0.f;
  if (pact) {
    const float4* wrow = (const float4*)(W_proj + (size_t)pcol * HDIM + pcl * 32);
    #pragma unroll
    for (int i = 0; i < 8; ++i) wp[i] = wrow[i];
    bp = b_proj[pcol];
  }

  for (int w = tid; w < 16 * 36; w += 512) { hs[0][w] = 0.f; hs[1][w] = 0.f; }

  // --- phase 0 (r8 exact): xp[:, block's 32 rows] = ys[:,T-1,:]@W_ih.T + b_ih
  {
    float* wih = xpl;                       // alias: 2624 <= 12288 floats
    for (int idx = tid; idx < 32 * IDIM; idx += 512) {
      int g = idx / IDIM, f = idx % IDIM;
      wih[g * 82 + f] = W_ih[(size_t)(nb * RPB + g) * IDIM + f];
    }
    if (tid < 32) bihs[tid] = b_ih[nb * RPB + tid];
    __syncthreads();
    const int g = tid & 31, b0 = tid >> 5;
    for (int pass = 0; pass < 32; ++pass) {
      int b = pass * 16 + b0;
      const float* yrow = ys + ((size_t)b * TT + (TT - 1)) * IDIM;
      float acc = bihs[g];
      #pragma unroll
      for (int f = 0; f < IDIM; f += 2) {
        float2 wv = *(const float2*)(&wih[g * 82 + f]);
        float2 yv = *(const float2*)(&yrow[f]);
        acc += wv.x * yv.x + wv.y * yv.y;
      }
      ag_storef(&xp[(size_t)b * GDIM + nb * RPB + g], acc);
    }
  }
  grid_barrier(bar, NB * 1u);        // once: xp visible + tag memset valid

  const int j = tid;                 // h element this thread gates
  const int jphys = (j >> 5) * 36 + (j & 31);

  for (int b = 0; b < BB; ++b) {
    const int cur = b & 1, nxt = cur ^ 1;

    // ---- xp slab refill every 8 steps (one burst; sc1 = AGENT-load flag) ----
    if ((b & 7) == 0) {
      const float* base = xp + (size_t)b * GDIM;   // steps b..b+7 = 12288 floats
      unsigned long long a0 = (unsigned long long)(base + (0 * 512 + tid) * 4);
      unsigned long long a1 = (unsigned long long)(base + (1 * 512 + tid) * 4);
      unsigned long long a2 = (unsigned long long)(base + (2 * 512 + tid) * 4);
      unsigned long long a3 = (unsigned long long)(base + (3 * 512 + tid) * 4);
      unsigned long long a4 = (unsigned long long)(base + (4 * 512 + tid) * 4);
      unsigned long long a5 = (unsigned long long)(base + (5 * 512 + tid) * 4);
      u32x4 q0, q1, q2, q3, q4, q5;
      asm volatile(
        "global_load_dwordx4 %0, %6, off sc1\n\t"
        "global_load_dwordx4 %1, %7, off sc1\n\t"
        "global_load_dwordx4 %2, %8, off sc1\n\t"
        "global_load_dwordx4 %3, %9, off sc1\n\t"
        "global_load_dwordx4 %4, %10, off sc1\n\t"
        "global_load_dwordx4 %5, %11, off sc1\n\t"
        "s_waitcnt vmcnt(0)"
        : "=&v"(q0), "=&v"(q1), "=&v"(q2), "=&v"(q3), "=&v"(q4), "=&v"(q5)
        : "v"(a0), "v"(a1), "v"(a2), "v"(a3), "v"(a4), "v"(a5)
        : "memory");
      union { u32x4 u; float4 f; } cv;
      float4* dst = (float4*)xpl;
      cv.u = q0; dst[0 * 512 + tid] = cv.f;
      cv.u = q1; dst[1 * 512 + tid] = cv.f;
      cv.u = q2; dst[2 * 512 + tid] = cv.f;
      cv.u = q3; dst[3 * 512 + tid] = cv.f;
      cv.u = q4; dst[4 * 512 + tid] = cv.f;
      cv.u = q5; dst[5 * 512 + tid] = cv.f;
    }

    // ---- my gh row partial (r8 exact): 32 cols of W_hh[row,:] . h_b ----
    const float* hbase = &hs[cur][c * 36];
    float a0 = 0.f, a1 = 0.f, a2 = 0.f, a3 = 0.f;
    #pragma unroll
    for (int i = 0; i < 8; ++i) {
      float4 h4 = ((const float4*)hbase)[i];
      a0 += wreg[i].x * h4.x; a1 += wreg[i].y * h4.y;
      a2 += wreg[i].z * h4.z; a3 += wreg[i].w * h4.w;
    }
    float acc = (a0 + a1) + (a2 + a3);
    acc += __shfl_xor(acc, 1);
    acc += __shfl_xor(acc, 2);
    acc += __shfl_xor(acc, 4);
    acc += __shfl_xor(acc, 8);
    unsigned long long* ghb = ghT + (size_t)cur * GDIM;
    if (c == 0) {
      union { float f; unsigned u; } cv; cv.f = acc + bhh_r;
      unsigned long long pv = ((unsigned long long)(unsigned)b << 32) | cv.u;
      ag_storeu(&ghb[row], pv);
    }

    // ---- proj for row b-1 (r8 exact; VGPR weights, poll-idle window) ----
    if (b >= 1 && pact) {
      const float* pb = &hs[cur][pcl * 36];
      float p0 = 0.f, p1 = 0.f, p2 = 0.f, p3 = 0.f;
      #pragma unroll
      for (int i = 0; i < 8; ++i) {
        float4 h4 = ((const float4*)pb)[i];
        p0 += wp[i].x * h4.x; p1 += wp[i].y * h4.y;
        p2 += wp[i].z * h4.z; p3 += wp[i].w * h4.w;
      }
      float pr = (p0 + p1) + (p2 + p3);
      pr += __shfl_xor(pr, 1);
      pr += __shfl_xor(pr, 2);
      pr += __shfl_xor(pr, 4);
      pr += __shfl_xor(pr, 8);
      if (pcl == 0) params[(size_t)(b - 1) * PDIM + pcol] = pr + bp;
    }

    // ---- designated pollers: line tid (8 words, 64B) -> gh_lds ----
    if (tid < 192) {
      unsigned long long la = (unsigned long long)(ghb + (size_t)tid * 8);
      const unsigned bb = (unsigned)b;
      int guard = 0;
      for (;;) {
        u32x4 A, B, C, D;
        asm volatile(
          "global_load_dwordx4 %0, %4, off sc1\n\t"
          "global_load_dwordx4 %1, %4, off offset:16 sc1\n\t"
          "global_load_dwordx4 %2, %4, off offset:32 sc1\n\t"
          "global_load_dwordx4 %3, %4, off offset:48 sc1\n\t"
          "s_waitcnt vmcnt(0)"
          : "=&v"(A), "=&v"(B), "=&v"(C), "=&v"(D) : "v"(la) : "memory");
        bool ok = (A.y == bb) & (A.w == bb) & (B.y == bb) & (B.w == bb)
                & (C.y == bb) & (C.w == bb) & (D.y == bb) & (D.w == bb);
        if (ok) {
          union { unsigned u; float f; } t;
          float4 v0, v1;
          t.u = A.x; v0.x = t.f; t.u = A.z; v0.y = t.f;
          t.u = B.x; v0.z = t.f; t.u = B.z; v0.w = t.f;
          t.u = C.x; v1.x = t.f; t.u = C.z; v1.y = t.f;
          t.u = D.x; v1.z = t.f; t.u = D.z; v1.w = t.f;
          float4* g4 = (float4*)(gh_lds + tid * 8);
          g4[0] = v0; g4[1] = v1;
          break;
        }
        if (++guard >= (1 << 20)) break;     // bounded: fail loudly, don't hang
        __builtin_amdgcn_s_sleep(1);         // backoff: cut IF request pressure
      }
    }
    __syncthreads();                         // gh_lds + xpl slab ready

    // ---- gates in consumer (r2/r8-proven math), inputs from LDS ----
    {
      const float* xs = xpl + (size_t)(b & 7) * GDIM;
      float xr = xs[j], xz = xs[512 + j], xn = xs[1024 + j];
      float hr = gh_lds[j], hz = gh_lds[512 + j], hn = gh_lds[1024 + j];
      float h_old = hs[cur][jphys];
      float r = 1.f / (1.f + __expf(-(xr + hr)));
      float z = 1.f / (1.f + __expf(-(xz + hz)));
      float e2 = __expf(2.f * (xn + r * hn));
      float n = 1.f - 2.f / (e2 + 1.f);      // tanh, overflow-safe
      float hnew = (1.f - z) * n + z * h_old;
      hs[nxt][jphys] = hnew;
    }
    __syncthreads();                         // h(b+1) complete; gh_lds reusable
  }

  // epilogue: proj for row 511 from hs[512&1] = hs[0] (r8 exact)
  if (pact) {
    const float* pb = &hs[0][pcl * 36];
    float p0 = 0.f, p1 = 0.f, p2 = 0.f, p3 = 0.f;
    #pragma unroll
    for (int i = 0; i < 8; ++i) {
      float4 h4 = ((const float4*)pb)[i];
      p0 += wp[i].x * h4.x; p1 += wp[i].y * h4.y;
      p2 += wp[i].z * h4.z; p3 += wp[i].w * h4.w;
    }
    float pr = (p0 + p1) + (p2 + p3);
    pr += __shfl_xor(pr, 1);
    pr += __shfl_xor(pr, 2);
    pr += __shfl_xor(pr, 4);
    pr += __shfl_xor(pr, 8);
    if (pcl == 0) params[(size_t)(BB - 1) * PDIM + pcol] = pr + bp;
  }
}

// samples[b,o] = sum_i w_i * (mu_i + (var_i+1e-6)*eps[i,b,o])
__global__ void mix_kernel(const float* __restrict__ params,
                           const float* __restrict__ eps,
                           float* __restrict__ out)
{
  int b = blockIdx.x, o = threadIdx.x;
  const float* pr = params + (size_t)b * PDIM;
  float s = 0.f;
  #pragma unroll
  for (int i = 0; i < G5; ++i) {
    float mu  = pr[i * ODIM + o];
    float var = pr[2 * i * ODIM + o] + 1e-6f;
    float w   = pr[2 * G5 * ODIM + i];
    float e   = eps[((size_t)i * BB + b) * ODIM + o];
    s += w * (mu + var * e);
  }
  out[(size_t)b * ODIM + o] = s;
}

extern "C" void kernel_launch(void* const* d_in, const int* in_sizes, int n_in,
                              void* d_out, int out_size, void* d_ws, size_t ws_size,
                              hipStream_t stream) {
  const float* ys     = (const float*)d_in[0];
  const float* W_ih   = (const float*)d_in[1];
  const float* W_hh   = (const float*)d_in[2];
  const float* b_ih   = (const float*)d_in[3];
  const float* b_hh   = (const float*)d_in[4];
  const float* W_proj = (const float*)d_in[5];
  const float* b_proj = (const float*)d_in[6];
  const float* eps    = (const float*)d_in[7];
  float* out = (float*)d_out;

  // workspace layout (same as r8)
  char* ws = (char*)d_ws;
  unsigned* bar           = (unsigned*)ws;                    // 256 B
  unsigned long long* ghT = (unsigned long long*)(ws + 256);  // 2*1536*8 = 24 KB
  float* xp     = (float*)(ws + 256 + 2 * GDIM * 8);          // 512*1536
  float* params = xp + (size_t)BB * GDIM;                     // 512*1285

  hipMemsetAsync(bar, 0, 256, stream);                 // barrier counter
  hipMemsetAsync(ghT, 0xFF, 2 * GDIM * 8, stream);     // tags invalid

  gru_kernel<<<NB, 512, 0, stream>>>(ys, W_ih, W_hh, b_ih, b_hh,
                                     W_proj, b_proj, xp, ghT, params, bar);

  mix_kernel<<<BB, ODIM, 0, stream>>>(params, eps, out);
}